// Round 13
// baseline (397.292 us; speedup 1.0000x reference)
//
#include <hip/hip_runtime.h>
#include <hip/hip_bf16.h>
#include <cstddef>

#define NN 100000
#define EE 1600000
#define CC 1000
#define NBK ((NN + 255) / 256)   // 391 dst buckets of 256 nodes
#define EPB 4096                  // edges per block in bucketize pass

#define FP8_SCALE 32.0f
#define FP8_INV   0.03125f

using short8 = __attribute__((ext_vector_type(8))) short;
using f32x4  = __attribute__((ext_vector_type(4))) float;
using f32x2  = __attribute__((ext_vector_type(2))) float;

__device__ __forceinline__ float bf2f(unsigned int u) {
    union { unsigned int i; float f; } x; x.i = u << 16; return x.f;
}
__device__ __forceinline__ unsigned short f2bf(float f) {
    __hip_bfloat16 h = __float2bfloat16(f);
    return *reinterpret_cast<unsigned short*>(&h);
}
__device__ __forceinline__ unsigned int pack2(float lo, float hi) {
    return ((unsigned int)f2bf(hi) << 16) | f2bf(lo);
}
__device__ __forceinline__ unsigned char f2fp8(float v) {
    unsigned int p = __builtin_amdgcn_cvt_pk_fp8_f32(v, v, 0, false);
    return (unsigned char)(p & 0xffu);
}
__device__ __forceinline__ f32x2 fp8x2f(unsigned int u16) {
    return __builtin_amdgcn_cvt_pk_f32_fp8(u16, false);
}

// ---------------- init: bucketCnt=0, bucketFill=0, commcnt=0 ----------------
__global__ void k_init(int* __restrict__ bucketCnt, int* __restrict__ bucketFill,
                       int* __restrict__ commcnt) {
    int i = blockIdx.x * 256 + threadIdx.x;   // grid covers 1024
    if (i < NBK) { bucketCnt[i] = 0; bucketFill[i] = 0; }
    if (i < CC) commcnt[i] = 0;
}

// ---------------- pass A0: bucket histogram (LDS-staged) ----------------
__global__ __launch_bounds__(256) void k_bhist(const int* __restrict__ dst,
                                               int* __restrict__ bucketCnt) {
    __shared__ int hist[NBK];
    int t = threadIdx.x;
    for (int i = t; i < NBK; i += 256) hist[i] = 0;
    __syncthreads();
    int base = blockIdx.x * EPB;
    for (int i = t; i < EPB; i += 256) {
        int e = base + i;
        if (e < EE) atomicAdd(&hist[dst[e] >> 8], 1);
    }
    __syncthreads();
    for (int i = t; i < NBK; i += 256)
        if (hist[i]) atomicAdd(&bucketCnt[i], hist[i]);
}

// ---------------- pass A-scan: exclusive scan of bucket counts (1 block) ----------------
__global__ void k_bscan(const int* __restrict__ bucketCnt, int* __restrict__ bucketBase) {
    __shared__ int sd[512];
    int t = threadIdx.x;
    int v = (t < NBK) ? bucketCnt[t] : 0;
    sd[t] = v;
    __syncthreads();
    for (int off = 1; off < 512; off <<= 1) {
        int x = (t >= off) ? sd[t - off] : 0;
        __syncthreads();
        sd[t] += x;
        __syncthreads();
    }
    if (t < NBK) bucketBase[t] = sd[t] - v;   // exclusive
    if (t == 0) bucketBase[NBK] = EE;
}

// ---------------- pass A1: partition edges into bucket regions ----------------
__global__ __launch_bounds__(256) void k_bucketize(
    const int* __restrict__ src, const int* __restrict__ dst,
    const int* __restrict__ bucketBase, int* __restrict__ bucketFill,
    int2* __restrict__ bkt) {
    __shared__ int hist[NBK];
    __shared__ int runPos[NBK];
    int t = threadIdx.x;
    for (int i = t; i < NBK; i += 256) hist[i] = 0;
    __syncthreads();
    int base = blockIdx.x * EPB;
    for (int i = t; i < EPB; i += 256) {
        int e = base + i;
        if (e < EE) atomicAdd(&hist[dst[e] >> 8], 1);
    }
    __syncthreads();
    for (int i = t; i < NBK; i += 256)
        runPos[i] = hist[i] ? (bucketBase[i] + atomicAdd(&bucketFill[i], hist[i])) : 0;
    __syncthreads();
    for (int i = t; i < EPB; i += 256) {
        int e = base + i;
        if (e < EE) {
            int d = dst[e];
            int pos = atomicAdd(&runPos[d >> 8], 1);
            bkt[pos] = make_int2(src[e], d);
        }
    }
}

// ---------------- pass B: per-bucket CSR finalize (rowofs, dis, commcnt, csr src) ----------------
__global__ __launch_bounds__(256) void k_csr(
    const int2* __restrict__ bkt, const int* __restrict__ bucketBase,
    const int* __restrict__ comm, int* __restrict__ commcnt,
    int* __restrict__ rowofs, float* __restrict__ dis, int* __restrict__ csr) {
    __shared__ int cnt[256], sd[256], cnt2[256];
    int b = blockIdx.x, t = threadIdx.x;
    int base = bucketBase[b], end = bucketBase[b + 1];
    int nodeBase = b << 8;
    cnt[t] = 0; cnt2[t] = 0;
    __syncthreads();
    for (int i = base + t; i < end; i += 256)
        atomicAdd(&cnt[bkt[i].y - nodeBase], 1);
    __syncthreads();
    int v = cnt[t];
    sd[t] = v;
    __syncthreads();
    for (int off = 1; off < 256; off <<= 1) {
        int x = (t >= off) ? sd[t - off] : 0;
        __syncthreads();
        sd[t] += x;
        __syncthreads();
    }
    int ofs = sd[t] - v;           // exclusive local offset
    sd[t] = ofs;
    int node = nodeBase + t;
    if (node < NN) {
        rowofs[node] = base + ofs;
        dis[node] = rsqrtf((float)v + 1.0f);
        atomicAdd(&commcnt[comm[node]], 1);
    }
    if (b == NBK - 1 && t == 0) rowofs[NN] = EE;
    __syncthreads();
    for (int i = base + t; i < end; i += 256) {
        int2 ed = bkt[i];
        int ld = ed.y - nodeBase;
        int p = atomicAdd(&cnt2[ld], 1);
        csr[base + sd[ld] + p] = ed.x;
    }
}

// ---------------- community scan (1 block over CC=1000) + zero commcnt ----------------
__global__ void k_scanc(int* __restrict__ commcnt, int* __restrict__ commofs) {
    __shared__ int sd[1024];
    int t = threadIdx.x;
    int v = (t < CC) ? commcnt[t] : 0;
    sd[t] = v;
    __syncthreads();
    for (int off = 1; off < 1024; off <<= 1) {
        int x = (t >= off) ? sd[t - off] : 0;
        __syncthreads();
        sd[t] += x;
        __syncthreads();
    }
    if (t < CC) {
        commofs[t] = sd[t] - v;        // exclusive
        commcnt[t] = 0;                // reset for fill pass
    }
    if (t == CC - 1) commofs[CC] = sd[t];
}

// ---------------- community member fill ----------------
__global__ void k_fillc(const int* __restrict__ comm, const int* __restrict__ commofs,
                        int* __restrict__ commcnt, int* __restrict__ members) {
    int i = blockIdx.x * 256 + threadIdx.x;
    if (i >= NN) return;
    int c = comm[i];
    int pos = commofs[c] + atomicAdd(&commcnt[c], 1);
    members[pos] = i;
}

// ---------------- weight convert+transpose (all 3): W[K][N] f32 -> Wt[N][K+8] bf16 ----------------
__global__ void k_wconv(const float* __restrict__ W3, unsigned short* __restrict__ W3t,
                        const float* __restrict__ Wc1, unsigned short* __restrict__ Wc1t,
                        const float* __restrict__ Wc2, unsigned short* __restrict__ Wc2t) {
    int y = blockIdx.y;
    int k = blockIdx.x * 256 + threadIdx.x;
    if (y < 320) {              // W3: K=320, N=320
        if (k < 328) W3t[(size_t)y * 328 + k] = (k < 320) ? f2bf(W3[(size_t)k * 320 + y]) : 0;
    } else if (y < 448) {       // Wc1: K=320, N=128
        int n = y - 320;
        if (k < 328) Wc1t[(size_t)n * 328 + k] = (k < 320) ? f2bf(Wc1[(size_t)k * 128 + n]) : 0;
    } else {                    // Wc2: K=128, N=128
        int n = y - 448;
        if (k < 136) Wc2t[(size_t)n * 136 + k] = (k < 128) ? f2bf(Wc2[(size_t)k * 128 + n]) : 0;
    }
}

// ---------------- embed (64 nodes/block): h0 = [relu(xW1+b1)|relu(xW2+b2)|id], bf16 ----------------
__global__ __launch_bounds__(256) void k_embed(
    const float* __restrict__ x, const float* __restrict__ id_emb,
    const float* __restrict__ W1, const float* __restrict__ b1,
    const float* __restrict__ W2, const float* __restrict__ b2,
    unsigned short* __restrict__ h0) {
    __shared__ float W1s[7][128];
    __shared__ float W2s[12][128];
    __shared__ float b1s[128], b2s[128];
    __shared__ float xs[64][20];
    int t = threadIdx.x;
    int base = blockIdx.x * 64;
    for (int i = t; i < 7 * 128; i += 256) ((float*)W1s)[i] = W1[i];
    for (int i = t; i < 12 * 128; i += 256) ((float*)W2s)[i] = W2[i];
    if (t < 128) { b1s[t] = b1[t]; b2s[t] = b2[t]; }
    for (int i = t; i < 64 * 19; i += 256) {
        int r = i / 19, cc = i % 19;
        int node = base + r;
        xs[r][cc] = (node < NN) ? x[(size_t)node * 19 + cc] : 0.f;
    }
    __syncthreads();
    int ln = t >> 6, lane = t & 63;
    int c2 = lane * 2;
    for (int nn = ln; nn < 64; nn += 4) {
        int node = base + nn;
        if (node >= NN) break;
        unsigned int* orow = (unsigned int*)(h0 + (size_t)node * 320);
        float a0 = b1s[c2], a1 = b1s[c2 + 1];
        #pragma unroll
        for (int k = 0; k < 7; ++k) {
            float xv = xs[nn][k];
            float2 w = *(const float2*)&W1s[k][c2];
            a0 += xv * w.x; a1 += xv * w.y;
        }
        orow[lane] = pack2(fmaxf(a0, 0.f), fmaxf(a1, 0.f));
        a0 = b2s[c2]; a1 = b2s[c2 + 1];
        #pragma unroll
        for (int k = 0; k < 12; ++k) {
            float xv = xs[nn][7 + k];
            float2 w = *(const float2*)&W2s[k][c2];
            a0 += xv * w.x; a1 += xv * w.y;
        }
        orow[64 + lane] = pack2(fmaxf(a0, 0.f), fmaxf(a1, 0.f));
        if (lane < 32) {
            float2 iv = *(const float2*)(id_emb + (size_t)node * 64 + c2);
            orow[128 + lane] = pack2(iv.x, iv.y);
        }
    }
}

// ---------------- fused emb3+conv1: hw8 = fp8(relu(h0@W3+b3) @ Wc1 * SCALE) ----------------
// 64 rows/block, 4 waves. Phase1: h1 acc (wave = 64 rows x 80 cols). Phase2: h1->LDS bf16
// (overwrites h0s). Phase3: conv1 (wave = 64 rows x 32 cols). Phase4: fp8 coalesced store.
__global__ __launch_bounds__(256) void k_fuse(
    const unsigned short* __restrict__ h0, const unsigned short* __restrict__ W3t,
    const float* __restrict__ b3, const unsigned short* __restrict__ Wc1t,
    unsigned char* __restrict__ hw8, int M) {
    __shared__ __align__(16) short h0s[64][328];   // 42 KB; becomes h1s after phase 2
    __shared__ __align__(16) short Bs[320][40];    // 25.6 KB; fp8 tile in phase 4
    int t = threadIdx.x;
    int rowBase = blockIdx.x * 64;
    int w = t >> 6, lane = t & 63;
    int fr = lane & 15, g = lane >> 4;
    // stage h0 row-panel once (full K)
    for (int c = t; c < 64 * 40; c += 256) {
        int r = c / 40, part = c % 40;
        int grow = rowBase + r;
        short8 v = {};
        if (grow < M) v = *(const short8*)(h0 + (size_t)grow * 320 + part * 8);
        *(short8*)&h0s[r][part * 8] = v;
    }
    // ---- phase 1: h1 = h0 @ W3 ---- (wave w owns cols [w*80, w*80+80))
    f32x4 acc1[4][5] = {};
    for (int kb = 0; kb < 320; kb += 32) {
        __syncthreads();                       // prev chunk's Bs reads done (and h0s staged)
        for (int c = t; c < 320 * 4; c += 256) {
            int r = c >> 2, q = c & 3;
            *(short8*)&Bs[r][q * 8] = *(const short8*)(W3t + (size_t)r * 328 + kb + q * 8);
        }
        __syncthreads();
        short8 a[4], b[5];
        #pragma unroll
        for (int rf = 0; rf < 4; ++rf)
            a[rf] = *(const short8*)&h0s[rf * 16 + fr][kb + g * 8];
        #pragma unroll
        for (int cf = 0; cf < 5; ++cf)
            b[cf] = *(const short8*)&Bs[w * 80 + cf * 16 + fr][g * 8];
        #pragma unroll
        for (int rf = 0; rf < 4; ++rf)
            #pragma unroll
            for (int cf = 0; cf < 5; ++cf)
                acc1[rf][cf] = __builtin_amdgcn_mfma_f32_16x16x32_bf16(a[rf], b[cf], acc1[rf][cf], 0, 0, 0);
    }
    __syncthreads();                           // all h0s reads complete
    // ---- phase 2: h1s = relu(acc1 + b3), bf16, in place of h0s ----
    #pragma unroll
    for (int cf = 0; cf < 5; ++cf) {
        int col = w * 80 + cf * 16 + fr;
        float bv = b3[col];
        #pragma unroll
        for (int rf = 0; rf < 4; ++rf) {
            #pragma unroll
            for (int r = 0; r < 4; ++r) {
                int row = rf * 16 + g * 4 + r;
                h0s[row][col] = (short)f2bf(fmaxf(acc1[rf][cf][r] + bv, 0.f));
            }
        }
    }
    // ---- phase 3: hw = h1 @ Wc1 ---- (wave w owns cols [w*32, w*32+32))
    f32x4 acc2[4][2] = {};
    for (int kb = 0; kb < 320; kb += 32) {
        __syncthreads();                       // h1s writes done / prev Bs reads done
        for (int c = t; c < 128 * 4; c += 256) {
            int r = c >> 2, q = c & 3;
            *(short8*)&Bs[r][q * 8] = *(const short8*)(Wc1t + (size_t)r * 328 + kb + q * 8);
        }
        __syncthreads();
        short8 a[4], b[2];
        #pragma unroll
        for (int rf = 0; rf < 4; ++rf)
            a[rf] = *(const short8*)&h0s[rf * 16 + fr][kb + g * 8];
        #pragma unroll
        for (int cf = 0; cf < 2; ++cf)
            b[cf] = *(const short8*)&Bs[w * 32 + cf * 16 + fr][g * 8];
        #pragma unroll
        for (int rf = 0; rf < 4; ++rf)
            #pragma unroll
            for (int cf = 0; cf < 2; ++cf)
                acc2[rf][cf] = __builtin_amdgcn_mfma_f32_16x16x32_bf16(a[rf], b[cf], acc2[rf][cf], 0, 0, 0);
    }
    // ---- phase 4: fp8 epilogue via LDS (Bs region) ----
    unsigned char* sb8 = (unsigned char*)Bs;   // 64x128 = 8 KB
    __syncthreads();
    #pragma unroll
    for (int cf = 0; cf < 2; ++cf) {
        int colL = w * 32 + cf * 16 + fr;
        #pragma unroll
        for (int rf = 0; rf < 4; ++rf) {
            #pragma unroll
            for (int r = 0; r < 4; ++r) {
                int row = rf * 16 + g * 4 + r;
                sb8[row * 128 + colL] = f2fp8(acc2[rf][cf][r] * FP8_SCALE);
            }
        }
    }
    __syncthreads();
    #pragma unroll
    for (int i = 0; i < 2; ++i) {
        int c16 = t + 256 * i;                 // 512 chunks of 16 B
        int row = c16 >> 3, col = (c16 & 7) * 16;
        int grow = rowBase + row;
        if (grow < M)
            *(int4*)(hw8 + (size_t)grow * 128 + col) = *(const int4*)&sb8[row * 128 + col];
    }
}

// ---------------- bf16 MFMA GEMM (conv2 only): double-buffered, fp8 out ----------------
template <int K, int N, int RELU, int OUT8>
__global__ __launch_bounds__(256) void k_bgemm(
    const unsigned short* __restrict__ A, const unsigned short* __restrict__ Bt,
    const float* __restrict__ bias, void* __restrict__ Cv, int M) {
    constexpr int NT = (N + 127) / 128;
    __shared__ __align__(16) short sbuf[2][10240];
    int t = threadIdx.x;
    int bid = blockIdx.x;
    int ct = bid % NT, rblk = bid / NT;
    int rowBase = rblk * 128, colBase = ct * 128;
    int wid = t >> 6, lane = t & 63;
    int wm = wid >> 1, wn = wid & 1;
    int fr = lane & 15, g = lane >> 4;
    int rr = t >> 2;
    int qq = (t & 3) * 8;
    f32x4 acc[4][4] = {};
    short8 z = {};
    short8 pA0, pA1, pB0, pB1;
    int grA0 = rowBase + rr, grA1 = grA0 + 64;
    int gcB0 = colBase + rr, gcB1 = gcB0 + 64;
    pA0 = (grA0 < M) ? *(const short8*)(A + (size_t)grA0 * K + qq) : z;
    pA1 = (grA1 < M) ? *(const short8*)(A + (size_t)grA1 * K + qq) : z;
    pB0 = (gcB0 < N) ? *(const short8*)(Bt + (size_t)gcB0 * (K + 8) + qq) : z;
    pB1 = (gcB1 < N) ? *(const short8*)(Bt + (size_t)gcB1 * (K + 8) + qq) : z;
    {
        short* As = sbuf[0];
        short* Bs = sbuf[0] + 128 * 40;
        *(short8*)&As[rr * 40 + qq]        = pA0;
        *(short8*)&As[(rr + 64) * 40 + qq] = pA1;
        *(short8*)&Bs[rr * 40 + qq]        = pB0;
        *(short8*)&Bs[(rr + 64) * 40 + qq] = pB1;
    }
    __syncthreads();
    int cur = 0;
    for (int kb = 0; kb < K; kb += 32) {
        bool more = (kb + 32 < K);
        if (more) {
            int kn = kb + 32;
            pA0 = (grA0 < M) ? *(const short8*)(A + (size_t)grA0 * K + kn + qq) : z;
            pA1 = (grA1 < M) ? *(const short8*)(A + (size_t)grA1 * K + kn + qq) : z;
            pB0 = (gcB0 < N) ? *(const short8*)(Bt + (size_t)gcB0 * (K + 8) + kn + qq) : z;
            pB1 = (gcB1 < N) ? *(const short8*)(Bt + (size_t)gcB1 * (K + 8) + kn + qq) : z;
        }
        const short* As = sbuf[cur];
        const short* Bs = sbuf[cur] + 128 * 40;
        short8 bfr[4];
        #pragma unroll
        for (int nf = 0; nf < 4; ++nf)
            bfr[nf] = *(const short8*)&Bs[(wn * 64 + nf * 16 + fr) * 40 + g * 8];
        #pragma unroll
        for (int mf = 0; mf < 4; ++mf) {
            short8 a = *(const short8*)&As[(wm * 64 + mf * 16 + fr) * 40 + g * 8];
            #pragma unroll
            for (int nf = 0; nf < 4; ++nf)
                acc[mf][nf] = __builtin_amdgcn_mfma_f32_16x16x32_bf16(a, bfr[nf], acc[mf][nf], 0, 0, 0);
        }
        if (more) {
            short* Asn = sbuf[cur ^ 1];
            short* Bsn = sbuf[cur ^ 1] + 128 * 40;
            *(short8*)&Asn[rr * 40 + qq]        = pA0;
            *(short8*)&Asn[(rr + 64) * 40 + qq] = pA1;
            *(short8*)&Bsn[rr * 40 + qq]        = pB0;
            *(short8*)&Bsn[(rr + 64) * 40 + qq] = pB1;
        }
        __syncthreads();
        cur ^= 1;
    }
    // fp8 epilogue
    unsigned char* sb8 = (unsigned char*)sbuf[0];
    #pragma unroll
    for (int nf = 0; nf < 4; ++nf) {
        int colL = wn * 64 + nf * 16 + fr;
        #pragma unroll
        for (int mf = 0; mf < 4; ++mf) {
            #pragma unroll
            for (int r = 0; r < 4; ++r) {
                int row = wm * 64 + mf * 16 + g * 4 + r;
                sb8[row * 128 + colL] = f2fp8(acc[mf][nf][r] * FP8_SCALE);
            }
        }
    }
    __syncthreads();
    #pragma unroll
    for (int i = 0; i < 4; ++i) {
        int off16 = t + 256 * i;
        int row = off16 >> 3;
        int col = (off16 & 7) * 16;
        int grow = rowBase + row;
        if (grow < M)
            *(int4*)((unsigned char*)Cv + (size_t)grow * N + col) =
                *(const int4*)&sb8[row * 128 + col];
    }
}

// ---------------- pure gather conv (fp8 in / bf16 out):
// h = relu(dis[d]*(sum hw8[src]*dis[src] + hw8[d]*dis[d])/SCALE + b) ----------------
__global__ __launch_bounds__(256) void k_gather(
    const int* __restrict__ rowofs, const int* __restrict__ csr,
    const float* __restrict__ dis, const unsigned char* __restrict__ hw8,
    const float* __restrict__ bias, unsigned short* __restrict__ hout) {
    int wid = blockIdx.x * 4 + (threadIdx.x >> 6);
    wid = __builtin_amdgcn_readfirstlane(wid);
    int lane = threadIdx.x & 63;
    if (wid >= NN) return;
    int ro = rowofs[wid], re = rowofs[wid + 1];
    int c = lane * 2;
    float dsd = dis[wid];
    unsigned int hv = *(const unsigned short*)(hw8 + (size_t)wid * 128 + c);
    f32x2 hf = fp8x2f(hv);
    float a0 = hf.x * dsd;
    float a1 = hf.y * dsd;
    int e = ro;
    for (; e + 16 <= re; e += 16) {
        int s[16]; float n[16]; unsigned int v[16];
        #pragma unroll
        for (int j = 0; j < 16; ++j) s[j] = csr[e + j];
        #pragma unroll
        for (int j = 0; j < 16; ++j) n[j] = dis[s[j]];
        #pragma unroll
        for (int j = 0; j < 16; ++j)
            v[j] = *(const unsigned short*)(hw8 + (size_t)s[j] * 128 + c);
        #pragma unroll
        for (int j = 0; j < 16; ++j) {
            f32x2 f = fp8x2f(v[j]);
            a0 += f.x * n[j];
            a1 += f.y * n[j];
        }
    }
    for (; e + 4 <= re; e += 4) {
        int s[4]; float n[4]; unsigned int v[4];
        #pragma unroll
        for (int j = 0; j < 4; ++j) s[j] = csr[e + j];
        #pragma unroll
        for (int j = 0; j < 4; ++j) n[j] = dis[s[j]];
        #pragma unroll
        for (int j = 0; j < 4; ++j)
            v[j] = *(const unsigned short*)(hw8 + (size_t)s[j] * 128 + c);
        #pragma unroll
        for (int j = 0; j < 4; ++j) {
            f32x2 f = fp8x2f(v[j]);
            a0 += f.x * n[j];
            a1 += f.y * n[j];
        }
    }
    for (; e < re; ++e) {
        int s0 = csr[e];
        float n0 = dis[s0];
        unsigned int v0 = *(const unsigned short*)(hw8 + (size_t)s0 * 128 + c);
        f32x2 f = fp8x2f(v0);
        a0 += f.x * n0;
        a1 += f.y * n0;
    }
    a0 = fmaxf(a0 * dsd * FP8_INV + bias[c], 0.f);
    a1 = fmaxf(a1 * dsd * FP8_INV + bias[c + 1], 0.f);
    *(unsigned int*)(hout + (size_t)wid * 128 + c) = pack2(a0, a1);
}

// ---------------- final: community pool (CSR, no atomics) + MLP ----------------
__global__ __launch_bounds__(128) void k_final(
    const unsigned short* __restrict__ h2, const unsigned short* __restrict__ h3,
    const int* __restrict__ commofs, const int* __restrict__ members,
    const float* __restrict__ Wl1, const float* __restrict__ bl1,
    const float* __restrict__ Wl2, const float* __restrict__ bl2,
    float* __restrict__ out) {
    __shared__ float zh[128];
    __shared__ float partial[2];
    int c = blockIdx.x, t = threadIdx.x;
    int ro = commofs[c], re = commofs[c + 1];
    float acc = 0.f;
    int e = ro;
    for (; e + 4 <= re; e += 4) {
        int m0 = members[e], m1 = members[e + 1];
        int m2 = members[e + 2], m3 = members[e + 3];
        acc += bf2f(h2[(size_t)m0 * 128 + t]) + bf2f(h3[(size_t)m0 * 128 + t]);
        acc += bf2f(h2[(size_t)m1 * 128 + t]) + bf2f(h3[(size_t)m1 * 128 + t]);
        acc += bf2f(h2[(size_t)m2 * 128 + t]) + bf2f(h3[(size_t)m2 * 128 + t]);
        acc += bf2f(h2[(size_t)m3 * 128 + t]) + bf2f(h3[(size_t)m3 * 128 + t]);
    }
    for (; e < re; ++e) {
        int m = members[e];
        acc += bf2f(h2[(size_t)m * 128 + t]) + bf2f(h3[(size_t)m * 128 + t]);
    }
    float invc = 1.0f / fmaxf((float)(re - ro), 1.0f);
    zh[t] = acc * invc;
    __syncthreads();
    float a = bl1[t];
    for (int k = 0; k < 128; ++k)
        a += zh[k] * (Wl1[(size_t)k * 128 + t] + Wl1[(size_t)(k + 128) * 128 + t]);
    float zv = fmaxf(a, 0.f);
    float p = zv * Wl2[t];
    #pragma unroll
    for (int off = 32; off > 0; off >>= 1) p += __shfl_down(p, off, 64);
    if ((t & 63) == 0) partial[t >> 6] = p;
    __syncthreads();
    if (t == 0) out[c] = partial[0] + partial[1] + bl2[0];
}

extern "C" void kernel_launch(void* const* d_in, const int* in_sizes, int n_in,
                              void* d_out, int out_size, void* d_ws, size_t ws_size,
                              hipStream_t stream) {
    const float* x       = (const float*)d_in[0];
    const int*   edge    = (const int*)d_in[1];
    const int*   comm    = (const int*)d_in[2];
    const float* id_emb  = (const float*)d_in[3];
    const float* W1      = (const float*)d_in[4];
    const float* b1      = (const float*)d_in[5];
    const float* W2      = (const float*)d_in[6];
    const float* b2      = (const float*)d_in[7];
    const float* W3      = (const float*)d_in[8];
    const float* b3      = (const float*)d_in[9];
    const float* Wc1     = (const float*)d_in[10];
    const float* bc1     = (const float*)d_in[11];
    const float* Wc2     = (const float*)d_in[12];
    const float* bc2     = (const float*)d_in[13];
    const float* Wl1     = (const float*)d_in[14];
    const float* bl1     = (const float*)d_in[15];
    const float* Wl2     = (const float*)d_in[16];
    const float* bl2     = (const float*)d_in[17];
    float* out = (float*)d_out;
    float* ws  = (float*)d_ws;

    const int* srcIdx = edge;
    const int* dstIdx = edge + EE;

    size_t o = 0;
    auto alloc = [&](size_t nfloats) {
        float* p = ws + o; o += (nfloats + 3) & ~(size_t)3; return p;
    };
    float* dis      = alloc(NN);
    int* rowofs     = (int*)alloc(NN + 8);
    int* bucketCnt  = (int*)alloc(NBK + 8);
    int* bucketBase = (int*)alloc(NBK + 8);
    int* bucketFill = (int*)alloc(NBK + 8);
    int* commcnt    = (int*)alloc(1024);
    int* commofs    = (int*)alloc(1024 + 8);
    int* members    = (int*)alloc(NN);
    int2* bkt       = (int2*)alloc((size_t)EE * 2);
    int* csr        = (int*)alloc(EE);
    unsigned short* W3t  = (unsigned short*)alloc(320 * 328 / 2);
    unsigned short* Wc1t = (unsigned short*)alloc(128 * 328 / 2);
    unsigned short* Wc2t = (unsigned short*)alloc(128 * 136 / 2);
    unsigned short* h0   = (unsigned short*)alloc((size_t)NN * 320 / 2);
    unsigned char*  hw8  = (unsigned char*)alloc((size_t)NN * 128 / 4);
    unsigned short* h2   = (unsigned short*)alloc((size_t)NN * 128 / 2);
    unsigned short* h3   = (unsigned short*)alloc((size_t)NN * 128 / 2);

    // ---- bucketed CSR build + degree norm + community CSR ----
    k_init<<<4, 256, 0, stream>>>(bucketCnt, bucketFill, commcnt);
    k_bhist<<<NBK, 256, 0, stream>>>(dstIdx, bucketCnt);
    k_bscan<<<1, 512, 0, stream>>>(bucketCnt, bucketBase);
    k_bucketize<<<NBK, 256, 0, stream>>>(srcIdx, dstIdx, bucketBase, bucketFill, bkt);
    k_csr<<<NBK, 256, 0, stream>>>(bkt, bucketBase, comm, commcnt, rowofs, dis, csr);
    k_scanc<<<1, 1024, 0, stream>>>(commcnt, commofs);
    k_fillc<<<NBK, 256, 0, stream>>>(comm, commofs, commcnt, members);

    // ---- weight convert/transpose to bf16 (one launch) ----
    k_wconv<<<dim3(2, 576), 256, 0, stream>>>(W3, W3t, Wc1, Wc1t, Wc2, Wc2t);

    // ---- embedding (bf16 out, 64 nodes/block) ----
    k_embed<<<(NN + 63) / 64, 256, 0, stream>>>(x, id_emb, W1, b1, W2, b2, h0);

    // ---- fused emb3 + conv1: hw8 = fp8(relu(h0@W3+b3) @ Wc1 * SCALE) ----
    k_fuse<<<(NN + 63) / 64, 256, 0, stream>>>(h0, W3t, b3, Wc1t, hw8, NN);
    k_gather<<<(NN + 3) / 4, 256, 0, stream>>>(rowofs, csr, dis, hw8, bc1, h2);
    // ---- conv2: hw8 = fp8(h2 @ Wc2 * SCALE) ----
    k_bgemm<128, 128, 0, 1><<<(NN + 127) / 128, 256, 0, stream>>>(h2, Wc2t, nullptr, hw8, NN);
    k_gather<<<(NN + 3) / 4, 256, 0, stream>>>(rowofs, csr, dis, hw8, bc2, h3);

    // ---- final: pool + MLP ----
    k_final<<<CC, 128, 0, stream>>>(h2, h3, commofs, members, Wl1, bl1, Wl2, bl2, out);
}

// Round 14
// 379.708 us; speedup vs baseline: 1.0463x; 1.0463x over previous
//
#include <hip/hip_runtime.h>
#include <hip/hip_bf16.h>
#include <cstddef>

#define NN 100000
#define EE 1600000
#define CC 1000
#define NBK ((NN + 255) / 256)   // 391 dst buckets of 256 nodes
#define EPB 4096                  // edges per block in bucketize pass

#define FP8_SCALE 32.0f
#define FP8_INV   0.03125f

using short8 = __attribute__((ext_vector_type(8))) short;
using f32x4  = __attribute__((ext_vector_type(4))) float;
using f32x2  = __attribute__((ext_vector_type(2))) float;

__device__ __forceinline__ float bf2f(unsigned int u) {
    union { unsigned int i; float f; } x; x.i = u << 16; return x.f;
}
__device__ __forceinline__ unsigned short f2bf(float f) {
    __hip_bfloat16 h = __float2bfloat16(f);
    return *reinterpret_cast<unsigned short*>(&h);
}
__device__ __forceinline__ unsigned int pack2(float lo, float hi) {
    return ((unsigned int)f2bf(hi) << 16) | f2bf(lo);
}
__device__ __forceinline__ unsigned char f2fp8(float v) {
    unsigned int p = __builtin_amdgcn_cvt_pk_fp8_f32(v, v, 0, false);
    return (unsigned char)(p & 0xffu);
}
__device__ __forceinline__ f32x2 fp8x2f(unsigned int u16) {
    return __builtin_amdgcn_cvt_pk_f32_fp8(u16, false);
}

// ---------------- init: bucketCnt=0, bucketFill=0, commcnt=0 ----------------
__global__ void k_init(int* __restrict__ bucketCnt, int* __restrict__ bucketFill,
                       int* __restrict__ commcnt) {
    int i = blockIdx.x * 256 + threadIdx.x;   // grid covers 1024
    if (i < NBK) { bucketCnt[i] = 0; bucketFill[i] = 0; }
    if (i < CC) commcnt[i] = 0;
}

// ---------------- pass A0: bucket histogram (LDS-staged) ----------------
__global__ __launch_bounds__(256) void k_bhist(const int* __restrict__ dst,
                                               int* __restrict__ bucketCnt) {
    __shared__ int hist[NBK];
    int t = threadIdx.x;
    for (int i = t; i < NBK; i += 256) hist[i] = 0;
    __syncthreads();
    int base = blockIdx.x * EPB;
    for (int i = t; i < EPB; i += 256) {
        int e = base + i;
        if (e < EE) atomicAdd(&hist[dst[e] >> 8], 1);
    }
    __syncthreads();
    for (int i = t; i < NBK; i += 256)
        if (hist[i]) atomicAdd(&bucketCnt[i], hist[i]);
}

// ---------------- pass A-scan: exclusive scan of bucket counts (1 block) ----------------
__global__ void k_bscan(const int* __restrict__ bucketCnt, int* __restrict__ bucketBase) {
    __shared__ int sd[512];
    int t = threadIdx.x;
    int v = (t < NBK) ? bucketCnt[t] : 0;
    sd[t] = v;
    __syncthreads();
    for (int off = 1; off < 512; off <<= 1) {
        int x = (t >= off) ? sd[t - off] : 0;
        __syncthreads();
        sd[t] += x;
        __syncthreads();
    }
    if (t < NBK) bucketBase[t] = sd[t] - v;   // exclusive
    if (t == 0) bucketBase[NBK] = EE;
}

// ---------------- pass A1: partition edges into bucket regions ----------------
__global__ __launch_bounds__(256) void k_bucketize(
    const int* __restrict__ src, const int* __restrict__ dst,
    const int* __restrict__ bucketBase, int* __restrict__ bucketFill,
    int2* __restrict__ bkt) {
    __shared__ int hist[NBK];
    __shared__ int runPos[NBK];
    int t = threadIdx.x;
    for (int i = t; i < NBK; i += 256) hist[i] = 0;
    __syncthreads();
    int base = blockIdx.x * EPB;
    for (int i = t; i < EPB; i += 256) {
        int e = base + i;
        if (e < EE) atomicAdd(&hist[dst[e] >> 8], 1);
    }
    __syncthreads();
    for (int i = t; i < NBK; i += 256)
        runPos[i] = hist[i] ? (bucketBase[i] + atomicAdd(&bucketFill[i], hist[i])) : 0;
    __syncthreads();
    for (int i = t; i < EPB; i += 256) {
        int e = base + i;
        if (e < EE) {
            int d = dst[e];
            int pos = atomicAdd(&runPos[d >> 8], 1);
            bkt[pos] = make_int2(src[e], d);
        }
    }
}

// ---------------- pass B: per-bucket CSR finalize (rowofs, dis, commcnt, csr src) ----------------
__global__ __launch_bounds__(256) void k_csr(
    const int2* __restrict__ bkt, const int* __restrict__ bucketBase,
    const int* __restrict__ comm, int* __restrict__ commcnt,
    int* __restrict__ rowofs, float* __restrict__ dis, int* __restrict__ csr) {
    __shared__ int cnt[256], sd[256], cnt2[256];
    int b = blockIdx.x, t = threadIdx.x;
    int base = bucketBase[b], end = bucketBase[b + 1];
    int nodeBase = b << 8;
    cnt[t] = 0; cnt2[t] = 0;
    __syncthreads();
    for (int i = base + t; i < end; i += 256)
        atomicAdd(&cnt[bkt[i].y - nodeBase], 1);
    __syncthreads();
    int v = cnt[t];
    sd[t] = v;
    __syncthreads();
    for (int off = 1; off < 256; off <<= 1) {
        int x = (t >= off) ? sd[t - off] : 0;
        __syncthreads();
        sd[t] += x;
        __syncthreads();
    }
    int ofs = sd[t] - v;           // exclusive local offset
    sd[t] = ofs;
    int node = nodeBase + t;
    if (node < NN) {
        rowofs[node] = base + ofs;
        dis[node] = rsqrtf((float)v + 1.0f);
        atomicAdd(&commcnt[comm[node]], 1);
    }
    if (b == NBK - 1 && t == 0) rowofs[NN] = EE;
    __syncthreads();
    for (int i = base + t; i < end; i += 256) {
        int2 ed = bkt[i];
        int ld = ed.y - nodeBase;
        int p = atomicAdd(&cnt2[ld], 1);
        csr[base + sd[ld] + p] = ed.x;
    }
}

// ---------------- community scan (1 block over CC=1000) + zero commcnt ----------------
__global__ void k_scanc(int* __restrict__ commcnt, int* __restrict__ commofs) {
    __shared__ int sd[1024];
    int t = threadIdx.x;
    int v = (t < CC) ? commcnt[t] : 0;
    sd[t] = v;
    __syncthreads();
    for (int off = 1; off < 1024; off <<= 1) {
        int x = (t >= off) ? sd[t - off] : 0;
        __syncthreads();
        sd[t] += x;
        __syncthreads();
    }
    if (t < CC) {
        commofs[t] = sd[t] - v;        // exclusive
        commcnt[t] = 0;                // reset for fill pass
    }
    if (t == CC - 1) commofs[CC] = sd[t];
}

// ---------------- community member fill ----------------
__global__ void k_fillc(const int* __restrict__ comm, const int* __restrict__ commofs,
                        int* __restrict__ commcnt, int* __restrict__ members) {
    int i = blockIdx.x * 256 + threadIdx.x;
    if (i >= NN) return;
    int c = comm[i];
    int pos = commofs[c] + atomicAdd(&commcnt[c], 1);
    members[pos] = i;
}

// ---------------- weight convert+transpose (all 3): W[K][N] f32 -> Wt[N][K+8] bf16 ----------------
__global__ void k_wconv(const float* __restrict__ W3, unsigned short* __restrict__ W3t,
                        const float* __restrict__ Wc1, unsigned short* __restrict__ Wc1t,
                        const float* __restrict__ Wc2, unsigned short* __restrict__ Wc2t) {
    int y = blockIdx.y;
    int k = blockIdx.x * 256 + threadIdx.x;
    if (y < 320) {              // W3: K=320, N=320
        if (k < 328) W3t[(size_t)y * 328 + k] = (k < 320) ? f2bf(W3[(size_t)k * 320 + y]) : 0;
    } else if (y < 448) {       // Wc1: K=320, N=128
        int n = y - 320;
        if (k < 328) Wc1t[(size_t)n * 328 + k] = (k < 320) ? f2bf(Wc1[(size_t)k * 128 + n]) : 0;
    } else {                    // Wc2: K=128, N=128
        int n = y - 448;
        if (k < 136) Wc2t[(size_t)n * 136 + k] = (k < 128) ? f2bf(Wc2[(size_t)k * 128 + n]) : 0;
    }
}

// ---------------- embed (64 nodes/block): h0 = [relu(xW1+b1)|relu(xW2+b2)|id], bf16 ----------------
__global__ __launch_bounds__(256) void k_embed(
    const float* __restrict__ x, const float* __restrict__ id_emb,
    const float* __restrict__ W1, const float* __restrict__ b1,
    const float* __restrict__ W2, const float* __restrict__ b2,
    unsigned short* __restrict__ h0) {
    __shared__ float W1s[7][128];
    __shared__ float W2s[12][128];
    __shared__ float b1s[128], b2s[128];
    __shared__ float xs[64][20];
    int t = threadIdx.x;
    int base = blockIdx.x * 64;
    for (int i = t; i < 7 * 128; i += 256) ((float*)W1s)[i] = W1[i];
    for (int i = t; i < 12 * 128; i += 256) ((float*)W2s)[i] = W2[i];
    if (t < 128) { b1s[t] = b1[t]; b2s[t] = b2[t]; }
    for (int i = t; i < 64 * 19; i += 256) {
        int r = i / 19, cc = i % 19;
        int node = base + r;
        xs[r][cc] = (node < NN) ? x[(size_t)node * 19 + cc] : 0.f;
    }
    __syncthreads();
    int ln = t >> 6, lane = t & 63;
    int c2 = lane * 2;
    for (int nn = ln; nn < 64; nn += 4) {
        int node = base + nn;
        if (node >= NN) break;
        unsigned int* orow = (unsigned int*)(h0 + (size_t)node * 320);
        float a0 = b1s[c2], a1 = b1s[c2 + 1];
        #pragma unroll
        for (int k = 0; k < 7; ++k) {
            float xv = xs[nn][k];
            float2 w = *(const float2*)&W1s[k][c2];
            a0 += xv * w.x; a1 += xv * w.y;
        }
        orow[lane] = pack2(fmaxf(a0, 0.f), fmaxf(a1, 0.f));
        a0 = b2s[c2]; a1 = b2s[c2 + 1];
        #pragma unroll
        for (int k = 0; k < 12; ++k) {
            float xv = xs[nn][7 + k];
            float2 w = *(const float2*)&W2s[k][c2];
            a0 += xv * w.x; a1 += xv * w.y;
        }
        orow[64 + lane] = pack2(fmaxf(a0, 0.f), fmaxf(a1, 0.f));
        if (lane < 32) {
            float2 iv = *(const float2*)(id_emb + (size_t)node * 64 + c2);
            orow[128 + lane] = pack2(iv.x, iv.y);
        }
    }
}

// ---------------- unified bf16 MFMA GEMM, reg-prefetch pipeline + coalesced epilogue ----------------
// OUT8=0: C bf16 [+bias+relu].  OUT8=1 (N must be 128): C fp8 scaled by FP8_SCALE.
template <int K, int N, int RELU, int OUT8>
__global__ __launch_bounds__(256) void k_bgemm(
    const unsigned short* __restrict__ A, const unsigned short* __restrict__ Bt,
    const float* __restrict__ bias, void* __restrict__ Cv, int M) {
    constexpr int NT = (N + 127) / 128;
    __shared__ __align__(16) short sbuf[2 * 128 * 40];   // 20480 B: As | Bs, reused by epilogue
    short (*As)[40] = (short(*)[40])sbuf;
    short (*Bs)[40] = (short(*)[40])(sbuf + 128 * 40);
    int t = threadIdx.x;
    int bid = blockIdx.x;
    int ct = bid % NT, rblk = bid / NT;
    int rowBase = rblk * 128, colBase = ct * 128;
    int wid = t >> 6, lane = t & 63;
    int wm = wid >> 1, wn = wid & 1;
    int fr = lane & 15, g = lane >> 4;
    int rr = t >> 2;              // 0..63 staging row
    int qq = (t & 3) * 8;         // k-subchunk
    f32x4 acc[4][4] = {};
    short8 z = {};
    short8 pA0, pA1, pB0, pB1;
    int grA0 = rowBase + rr, grA1 = grA0 + 64;
    int gcB0 = colBase + rr, gcB1 = gcB0 + 64;
    // prefetch k=0
    pA0 = (grA0 < M) ? *(const short8*)(A + (size_t)grA0 * K + qq) : z;
    pA1 = (grA1 < M) ? *(const short8*)(A + (size_t)grA1 * K + qq) : z;
    pB0 = (gcB0 < N) ? *(const short8*)(Bt + (size_t)gcB0 * (K + 8) + qq) : z;
    pB1 = (gcB1 < N) ? *(const short8*)(Bt + (size_t)gcB1 * (K + 8) + qq) : z;
    for (int kb = 0; kb < K; kb += 32) {
        __syncthreads();                    // LDS consumers of prev step done
        *(short8*)&As[rr][qq]      = pA0;
        *(short8*)&As[rr + 64][qq] = pA1;
        *(short8*)&Bs[rr][qq]      = pB0;
        *(short8*)&Bs[rr + 64][qq] = pB1;
        __syncthreads();                    // LDS ready
        if (kb + 32 < K) {                  // issue next-step loads under MFMA
            int kn = kb + 32;
            pA0 = (grA0 < M) ? *(const short8*)(A + (size_t)grA0 * K + kn + qq) : z;
            pA1 = (grA1 < M) ? *(const short8*)(A + (size_t)grA1 * K + kn + qq) : z;
            pB0 = (gcB0 < N) ? *(const short8*)(Bt + (size_t)gcB0 * (K + 8) + kn + qq) : z;
            pB1 = (gcB1 < N) ? *(const short8*)(Bt + (size_t)gcB1 * (K + 8) + kn + qq) : z;
        }
        short8 bfr[4];
        #pragma unroll
        for (int nf = 0; nf < 4; ++nf)
            bfr[nf] = *(const short8*)&Bs[wn * 64 + nf * 16 + fr][g * 8];
        #pragma unroll
        for (int mf = 0; mf < 4; ++mf) {
            short8 a = *(const short8*)&As[wm * 64 + mf * 16 + fr][g * 8];
            #pragma unroll
            for (int nf = 0; nf < 4; ++nf)
                acc[mf][nf] = __builtin_amdgcn_mfma_f32_16x16x32_bf16(a, bfr[nf], acc[mf][nf], 0, 0, 0);
        }
    }
    // ---- epilogue: LDS transpose -> coalesced 16B stores ----
    if (!OUT8) {
        unsigned short* sb = (unsigned short*)sbuf;
        #pragma unroll
        for (int cc = 0; cc < 2; ++cc) {
            int cbase = colBase + cc * 64;
            if (cbase < N) {                       // uniform per block
                __syncthreads();
                if (wn == cc) {
                    #pragma unroll
                    for (int nf = 0; nf < 4; ++nf) {
                        int colL = nf * 16 + fr;
                        float bv = RELU ? bias[cbase + colL] : 0.f;
                        #pragma unroll
                        for (int mf = 0; mf < 4; ++mf) {
                            #pragma unroll
                            for (int r = 0; r < 4; ++r) {
                                int row = wm * 64 + mf * 16 + g * 4 + r;
                                float v = acc[mf][nf][r];
                                if (RELU) v = fmaxf(v + bv, 0.f);
                                sb[row * 64 + colL] = f2bf(v);
                            }
                        }
                    }
                }
                __syncthreads();
                #pragma unroll
                for (int i = 0; i < 4; ++i) {
                    int off8 = t + 256 * i;        // 16-B chunk id (1024 total)
                    int row = off8 >> 3;
                    int col = (off8 & 7) * 8;
                    int grow = rowBase + row;
                    if (grow < M)
                        *(short8*)((unsigned short*)Cv + (size_t)grow * N + cbase + col) =
                            *(const short8*)&sb[row * 64 + col];
                }
            }
        }
    } else {
        unsigned char* sb8 = (unsigned char*)sbuf;  // 128x128 fp8 tile = 16 KB
        __syncthreads();
        #pragma unroll
        for (int nf = 0; nf < 4; ++nf) {
            int colL = wn * 64 + nf * 16 + fr;
            #pragma unroll
            for (int mf = 0; mf < 4; ++mf) {
                #pragma unroll
                for (int r = 0; r < 4; ++r) {
                    int row = wm * 64 + mf * 16 + g * 4 + r;
                    sb8[row * 128 + colL] = f2fp8(acc[mf][nf][r] * FP8_SCALE);
                }
            }
        }
        __syncthreads();
        #pragma unroll
        for (int i = 0; i < 4; ++i) {
            int off16 = t + 256 * i;               // 16-B chunk id (1024 total)
            int row = off16 >> 3;
            int col = (off16 & 7) * 16;
            int grow = rowBase + row;
            if (grow < M)
                *(int4*)((unsigned char*)Cv + (size_t)grow * N + col) =
                    *(const int4*)&sb8[row * 128 + col];
        }
    }
}

// ---------------- pure gather conv (fp8 in / bf16 out):
// h = relu(dis[d]*(sum hw8[src]*dis[src] + hw8[d]*dis[d])/SCALE + b) ----------------
__global__ __launch_bounds__(256) void k_gather(
    const int* __restrict__ rowofs, const int* __restrict__ csr,
    const float* __restrict__ dis, const unsigned char* __restrict__ hw8,
    const float* __restrict__ bias, unsigned short* __restrict__ hout) {
    int wid = blockIdx.x * 4 + (threadIdx.x >> 6);
    wid = __builtin_amdgcn_readfirstlane(wid);
    int lane = threadIdx.x & 63;
    if (wid >= NN) return;
    int ro = rowofs[wid], re = rowofs[wid + 1];
    int c = lane * 2;
    float dsd = dis[wid];
    unsigned int hv = *(const unsigned short*)(hw8 + (size_t)wid * 128 + c);
    f32x2 hf = fp8x2f(hv);
    float a0 = hf.x * dsd;           // scaled space; final multiply by dsd
    float a1 = hf.y * dsd;
    int e = ro;
    for (; e + 16 <= re; e += 16) {
        int s[16]; float n[16]; unsigned int v[16];
        #pragma unroll
        for (int j = 0; j < 16; ++j) s[j] = csr[e + j];
        #pragma unroll
        for (int j = 0; j < 16; ++j) n[j] = dis[s[j]];
        #pragma unroll
        for (int j = 0; j < 16; ++j)
            v[j] = *(const unsigned short*)(hw8 + (size_t)s[j] * 128 + c);
        #pragma unroll
        for (int j = 0; j < 16; ++j) {
            f32x2 f = fp8x2f(v[j]);
            a0 += f.x * n[j];
            a1 += f.y * n[j];
        }
    }
    for (; e + 4 <= re; e += 4) {
        int s[4]; float n[4]; unsigned int v[4];
        #pragma unroll
        for (int j = 0; j < 4; ++j) s[j] = csr[e + j];
        #pragma unroll
        for (int j = 0; j < 4; ++j) n[j] = dis[s[j]];
        #pragma unroll
        for (int j = 0; j < 4; ++j)
            v[j] = *(const unsigned short*)(hw8 + (size_t)s[j] * 128 + c);
        #pragma unroll
        for (int j = 0; j < 4; ++j) {
            f32x2 f = fp8x2f(v[j]);
            a0 += f.x * n[j];
            a1 += f.y * n[j];
        }
    }
    for (; e < re; ++e) {
        int s0 = csr[e];
        float n0 = dis[s0];
        unsigned int v0 = *(const unsigned short*)(hw8 + (size_t)s0 * 128 + c);
        f32x2 f = fp8x2f(v0);
        a0 += f.x * n0;
        a1 += f.y * n0;
    }
    a0 = fmaxf(a0 * dsd * FP8_INV + bias[c], 0.f);
    a1 = fmaxf(a1 * dsd * FP8_INV + bias[c + 1], 0.f);
    *(unsigned int*)(hout + (size_t)wid * 128 + c) = pack2(a0, a1);
}

// ---------------- final: community pool (CSR, no atomics) + MLP ----------------
__global__ __launch_bounds__(128) void k_final(
    const unsigned short* __restrict__ h2, const unsigned short* __restrict__ h3,
    const int* __restrict__ commofs, const int* __restrict__ members,
    const float* __restrict__ Wl1, const float* __restrict__ bl1,
    const float* __restrict__ Wl2, const float* __restrict__ bl2,
    float* __restrict__ out) {
    __shared__ float zh[128];
    __shared__ float partial[2];
    int c = blockIdx.x, t = threadIdx.x;
    int ro = commofs[c], re = commofs[c + 1];
    float acc = 0.f;
    int e = ro;
    for (; e + 4 <= re; e += 4) {
        int m0 = members[e], m1 = members[e + 1];
        int m2 = members[e + 2], m3 = members[e + 3];
        acc += bf2f(h2[(size_t)m0 * 128 + t]) + bf2f(h3[(size_t)m0 * 128 + t]);
        acc += bf2f(h2[(size_t)m1 * 128 + t]) + bf2f(h3[(size_t)m1 * 128 + t]);
        acc += bf2f(h2[(size_t)m2 * 128 + t]) + bf2f(h3[(size_t)m2 * 128 + t]);
        acc += bf2f(h2[(size_t)m3 * 128 + t]) + bf2f(h3[(size_t)m3 * 128 + t]);
    }
    for (; e < re; ++e) {
        int m = members[e];
        acc += bf2f(h2[(size_t)m * 128 + t]) + bf2f(h3[(size_t)m * 128 + t]);
    }
    float invc = 1.0f / fmaxf((float)(re - ro), 1.0f);
    zh[t] = acc * invc;
    __syncthreads();
    float a = bl1[t];
    for (int k = 0; k < 128; ++k)
        a += zh[k] * (Wl1[(size_t)k * 128 + t] + Wl1[(size_t)(k + 128) * 128 + t]);
    float zv = fmaxf(a, 0.f);
    float p = zv * Wl2[t];
    #pragma unroll
    for (int off = 32; off > 0; off >>= 1) p += __shfl_down(p, off, 64);
    if ((t & 63) == 0) partial[t >> 6] = p;
    __syncthreads();
    if (t == 0) out[c] = partial[0] + partial[1] + bl2[0];
}

extern "C" void kernel_launch(void* const* d_in, const int* in_sizes, int n_in,
                              void* d_out, int out_size, void* d_ws, size_t ws_size,
                              hipStream_t stream) {
    const float* x       = (const float*)d_in[0];
    const int*   edge    = (const int*)d_in[1];
    const int*   comm    = (const int*)d_in[2];
    const float* id_emb  = (const float*)d_in[3];
    const float* W1      = (const float*)d_in[4];
    const float* b1      = (const float*)d_in[5];
    const float* W2      = (const float*)d_in[6];
    const float* b2      = (const float*)d_in[7];
    const float* W3      = (const float*)d_in[8];
    const float* b3      = (const float*)d_in[9];
    const float* Wc1     = (const float*)d_in[10];
    const float* bc1     = (const float*)d_in[11];
    const float* Wc2     = (const float*)d_in[12];
    const float* bc2     = (const float*)d_in[13];
    const float* Wl1     = (const float*)d_in[14];
    const float* bl1     = (const float*)d_in[15];
    const float* Wl2     = (const float*)d_in[16];
    const float* bl2     = (const float*)d_in[17];
    float* out = (float*)d_out;
    float* ws  = (float*)d_ws;

    const int* srcIdx = edge;
    const int* dstIdx = edge + EE;

    size_t o = 0;
    auto alloc = [&](size_t nfloats) {
        float* p = ws + o; o += (nfloats + 3) & ~(size_t)3; return p;
    };
    float* dis      = alloc(NN);
    int* rowofs     = (int*)alloc(NN + 8);
    int* bucketCnt  = (int*)alloc(NBK + 8);
    int* bucketBase = (int*)alloc(NBK + 8);
    int* bucketFill = (int*)alloc(NBK + 8);
    int* commcnt    = (int*)alloc(1024);
    int* commofs    = (int*)alloc(1024 + 8);
    int* members    = (int*)alloc(NN);
    int2* bkt       = (int2*)alloc((size_t)EE * 2);
    int* csr        = (int*)alloc(EE);
    unsigned short* W3t  = (unsigned short*)alloc(320 * 328 / 2);
    unsigned short* Wc1t = (unsigned short*)alloc(128 * 328 / 2);
    unsigned short* Wc2t = (unsigned short*)alloc(128 * 136 / 2);
    unsigned short* h0   = (unsigned short*)alloc((size_t)NN * 320 / 2);
    unsigned short* h1   = (unsigned short*)alloc((size_t)NN * 320 / 2);
    unsigned char*  hw8  = (unsigned char*)alloc((size_t)NN * 128 / 4);
    unsigned short* h2   = (unsigned short*)alloc((size_t)NN * 128 / 2);
    unsigned short* h3   = (unsigned short*)alloc((size_t)NN * 128 / 2);

    // ---- bucketed CSR build + degree norm + community CSR ----
    k_init<<<4, 256, 0, stream>>>(bucketCnt, bucketFill, commcnt);
    k_bhist<<<NBK, 256, 0, stream>>>(dstIdx, bucketCnt);
    k_bscan<<<1, 512, 0, stream>>>(bucketCnt, bucketBase);
    k_bucketize<<<NBK, 256, 0, stream>>>(srcIdx, dstIdx, bucketBase, bucketFill, bkt);
    k_csr<<<NBK, 256, 0, stream>>>(bkt, bucketBase, comm, commcnt, rowofs, dis, csr);
    k_scanc<<<1, 1024, 0, stream>>>(commcnt, commofs);
    k_fillc<<<NBK, 256, 0, stream>>>(comm, commofs, commcnt, members);

    // ---- weight convert/transpose to bf16 (one launch) ----
    k_wconv<<<dim3(2, 576), 256, 0, stream>>>(W3, W3t, Wc1, Wc1t, Wc2, Wc2t);

    // ---- embedding (bf16 out, 64 nodes/block) ----
    k_embed<<<(NN + 63) / 64, 256, 0, stream>>>(x, id_emb, W1, b1, W2, b2, h0);

    int rb = (NN + 127) / 128;   // 782
    // h1 = relu(h0 @ W3 + b3)   (3 col-tiles, ct fastest for A locality)
    k_bgemm<320, 320, 1, 0><<<rb * 3, 256, 0, stream>>>(h0, W3t, b3, h1, NN);
    // ---- conv1: hw8 = fp8(h1 @ Wc1 * SCALE) ----
    k_bgemm<320, 128, 0, 1><<<rb, 256, 0, stream>>>(h1, Wc1t, nullptr, hw8, NN);
    k_gather<<<(NN + 3) / 4, 256, 0, stream>>>(rowofs, csr, dis, hw8, bc1, h2);
    // ---- conv2: hw8 = fp8(h2 @ Wc2 * SCALE) ----
    k_bgemm<128, 128, 0, 1><<<rb, 256, 0, stream>>>(h2, Wc2t, nullptr, hw8, NN);
    k_gather<<<(NN + 3) / 4, 256, 0, stream>>>(rowofs, csr, dis, hw8, bc2, h3);

    // ---- final: pool + MLP ----
    k_final<<<CC, 128, 0, stream>>>(h2, h3, commofs, members, Wl1, bl1, Wl2, bl2, out);
}